// Round 7
// baseline (261.266 us; speedup 1.0000x reference)
//
#include <hip/hip_runtime.h>

#define B_N 131072

using bfrag_t = __attribute__((ext_vector_type(8))) short;  // 8 bf16 (MFMA A/B frag)
using acc_t   = __attribute__((ext_vector_type(4))) float;  // 4 fp32 (MFMA C/D frag)
using v4f     = __attribute__((ext_vector_type(4))) float;
using i32x4_t = __attribute__((ext_vector_type(4))) int;

__device__ __forceinline__ unsigned short f2bf(float f) {
  unsigned int u = __float_as_uint(f);
  u += 0x7FFFu + ((u >> 16) & 1u);   // RNE
  return (unsigned short)(u >> 16);
}

__device__ __forceinline__ unsigned int pk2bf(float x, float y) {
  return (unsigned int)f2bf(x) | ((unsigned int)f2bf(y) << 16);
}

// async global->LDS, 16B per lane; lds base must be wave-uniform (lane-linear dest)
__device__ __forceinline__ void gload_lds16(const void* g, void* l) {
  __builtin_amdgcn_global_load_lds((const __attribute__((address_space(1))) void*)g,
                                   (__attribute__((address_space(3))) void*)l, 16, 0, 0);
}

// exact GELU: 0.5x(1+erf(x/sqrt2)); erf via Abramowitz-Stegun 7.1.26, |eps|<=1.5e-7
__device__ __forceinline__ float gelu_f(float x) {
  float ax = fabsf(x) * 0.70710678118654752f;
  float t  = __builtin_amdgcn_rcpf(fmaf(0.3275911f, ax, 1.0f));
  float p  = fmaf(1.061405429f, t, -1.453152027f);
  p = fmaf(p, t, 1.421413741f);
  p = fmaf(p, t, -0.284496736f);
  p = fmaf(p, t, 0.254829592f);
  p = p * t;
  float e  = __expf(-ax * ax);
  float er = fmaf(-p, e, 1.0f);
  er = (x < 0.0f) ? -er : er;
  return 0.5f * x * (1.0f + er);
}

// quad_perm DPP (compile-time ctrl): [1,0,3,2]=0xB1 pair-swap, [2,3,0,1]=0x4E half-swap
#define QP_F(v, CTRL) __int_as_float(__builtin_amdgcn_mov_dpp(__float_as_int(v), (CTRL), 0xF, 0xF, false))
#define QP_I(v, CTRL) __builtin_amdgcn_mov_dpp((v), (CTRL), 0xF, 0xF, false)

// ---------------- K1: prepack (round-0 version + counter zeroing) ----------------
__global__ __launch_bounds__(256) void prepack2_k(
    const float* __restrict__ Wr1, const float* __restrict__ br1,
    const float* __restrict__ Wr2, const float* __restrict__ br2,
    const float* __restrict__ W1, const float* __restrict__ W2,
    float* __restrict__ RW, short* __restrict__ W1s, short* __restrict__ W2s,
    unsigned int* __restrict__ counts) {
  int gt = blockIdx.x * 256 + threadIdx.x;   // grid 64 -> 16384 threads
  if (gt < 4) counts[gt] = 0u;
  for (int idx = gt; idx < 142 * 64; idx += 16384) {
    int row = idx >> 6, j = idx & 63; float val;
    if (row < 136)      val = Wr1[row * 64 + j];
    else if (row == 136) val = br1[j];
    else if (row < 141) val = Wr2[(row - 137) * 64 + j];
    else                val = (j < 4) ? br2[j] : 0.0f;
    RW[idx] = val;
  }
  for (int ch = gt; ch < 8192; ch += 16384) {  // W1: (4,128,128) [t][k][n]
    int t = ch >> 11, r = (ch >> 4) & 127, c = ch & 15;
    const float* src = W1 + t * 16384 + r;     // stride 128 over k
    short* dst = W1s + (t * 128 + r) * 128 + ((c ^ (r & 15)) * 8);
    #pragma unroll
    for (int m = 0; m < 8; m++) dst[m] = (short)f2bf(src[(c * 8 + m) * 128]);
  }
  for (int ch = gt; ch < 4096; ch += 16384) {  // W2: (4,128,64) [t][k][d]
    int t = ch >> 10, d = (ch >> 4) & 63, c = ch & 15;
    const float* src = W2 + t * 8192 + d;      // stride 64 over k
    short* dst = W2s + (t * 64 + d) * 128 + ((c ^ (d & 15)) * 8);
    #pragma unroll
    for (int m = 0; m < 8; m++) dst[m] = (short)f2bf(src[(c * 8 + m) * 64]);
  }
}

// ---------------- K2: router v12 — weights via vector L1/L2, LDS holds only x ----
// v11's compute (C=8 ch x S=2 samples per lane; identical fp32 fma chain) but all
// weight/bias reads come from RW in GLOBAL memory (v4f, 8-lane-dup -> 8x16B lines,
// L1/L2-hot: per-CU demand ~5.7 TB/s vs 34.5 L2 ceiling). LDS = X+P only (35.6KB)
// -> 4 blocks/CU = 4 waves/SIMD (was 2). Round-4's scalar-path failure was the
// 16KB K$; the vector path has 32KB L1 + L2 and per-wave TLP. Argmax-flip safe:
// br1 -> a_i*W[i] (i asc) -> b_i*W[64+i] -> pos (acc1); a/b swapped (acc2); gelu;
// br2 + h_j asc; quad-DPP argmax (strict >, lowest index wins).
__global__ __launch_bounds__(256) void router12_k(
    const float* __restrict__ a, const float* __restrict__ b,
    const float* __restrict__ pos, const float* __restrict__ RW,
    unsigned char* __restrict__ r1, unsigned char* __restrict__ r2,
    unsigned int* __restrict__ gcounts) {
  __shared__ float SB[8896];   // X [0,8320) s*130 (a|b) | P [8320,8896) s*9
                               // after barrier: HX float2 [s][j] stride 66 overlays
  __shared__ unsigned int hcnt[4];
  const int PO = 8320;
  int tid = threadIdx.x;
  int s0 = blockIdx.x * 64;
  if (tid < 4) hcnt[tid] = 0u;

  // X natural: X[s][0..63]=a, [64..127]=b ; stride 130 (float2-aligned stores)
  #pragma unroll
  for (int it = 0; it < 8; it++) {
    int idx = it * 256 + tid;            // 2048 v4f chunks = 64 samples x 32
    int s = idx >> 5, c = idx & 31;
    const float* src = (c < 16) ? (a + (size_t)(s0 + s) * 64 + c * 4)
                                : (b + (size_t)(s0 + s) * 64 + (c - 16) * 4);
    v4f v = *(const v4f*)src;
    float* dst = SB + s * 130 + ((c < 16) ? c * 4 : 64 + (c - 16) * 4);
    *(float2*)dst = float2{v[0], v[1]};
    *(float2*)(dst + 2) = float2{v[2], v[3]};
  }
  // P[s][c], stride 9
  #pragma unroll
  for (int r = 0; r < 2; r++) {
    int idx = r * 256 + tid;             // 512 = 64 samples x 8
    int s = idx >> 3, c = idx & 7;
    SB[PO + s * 9 + c] = pos[(size_t)(s0 + s) * 8 + c];
  }
  __syncthreads();

  int sp = tid >> 3, jg = tid & 7;       // samples {sp, sp+32}; channels jg*8..+7
  const float* Xs0 = SB + sp * 130;
  const float* Xs1 = SB + (sp + 32) * 130;
  const float* Wg = RW + jg * 8;         // this lane's weight-column base (global)
  v4f acc1[2][2], acc2[2][2];            // [sample][v4f-half of 8 channels]
  {
    v4f bi0 = *(const v4f*)(RW + 136 * 64 + jg * 8);
    v4f bi1 = *(const v4f*)(RW + 136 * 64 + jg * 8 + 4);
    acc1[0][0] = bi0; acc1[0][1] = bi1; acc1[1][0] = bi0; acc1[1][1] = bi1;
    acc2[0][0] = bi0; acc2[0][1] = bi1; acc2[1][0] = bi0; acc2[1][1] = bi1;
  }
  // rows 0..63: acc1 += a_i*W[i], acc2 += b_i*W[i]  (i ascending)
  #pragma unroll 4
  for (int i = 0; i < 64; i++) {
    float xa0 = Xs0[i], xb0 = Xs0[64 + i];     // one ds_read2_b32
    float xa1 = Xs1[i], xb1 = Xs1[64 + i];     // one ds_read2_b32
    const v4f* w = (const v4f*)(Wg + i * 64);  // global, L1/L2-hot
    v4f w0 = w[0], w1 = w[1];
    v4f A0 = {xa0, xa0, xa0, xa0}, B0 = {xb0, xb0, xb0, xb0};
    v4f A1 = {xa1, xa1, xa1, xa1}, B1 = {xb1, xb1, xb1, xb1};
    acc1[0][0] = __builtin_elementwise_fma(A0, w0, acc1[0][0]);
    acc1[0][1] = __builtin_elementwise_fma(A0, w1, acc1[0][1]);
    acc2[0][0] = __builtin_elementwise_fma(B0, w0, acc2[0][0]);
    acc2[0][1] = __builtin_elementwise_fma(B0, w1, acc2[0][1]);
    acc1[1][0] = __builtin_elementwise_fma(A1, w0, acc1[1][0]);
    acc1[1][1] = __builtin_elementwise_fma(A1, w1, acc1[1][1]);
    acc2[1][0] = __builtin_elementwise_fma(B1, w0, acc2[1][0]);
    acc2[1][1] = __builtin_elementwise_fma(B1, w1, acc2[1][1]);
  }
  // rows 64..127: acc1 += b_i*W[64+i], acc2 += a_i*W[64+i]
  #pragma unroll 4
  for (int i = 0; i < 64; i++) {
    float xa0 = Xs0[i], xb0 = Xs0[64 + i];
    float xa1 = Xs1[i], xb1 = Xs1[64 + i];
    const v4f* w = (const v4f*)(Wg + (64 + i) * 64);
    v4f w0 = w[0], w1 = w[1];
    v4f A0 = {xa0, xa0, xa0, xa0}, B0 = {xb0, xb0, xb0, xb0};
    v4f A1 = {xa1, xa1, xa1, xa1}, B1 = {xb1, xb1, xb1, xb1};
    acc1[0][0] = __builtin_elementwise_fma(B0, w0, acc1[0][0]);
    acc1[0][1] = __builtin_elementwise_fma(B0, w1, acc1[0][1]);
    acc2[0][0] = __builtin_elementwise_fma(A0, w0, acc2[0][0]);
    acc2[0][1] = __builtin_elementwise_fma(A0, w1, acc2[0][1]);
    acc1[1][0] = __builtin_elementwise_fma(B1, w0, acc1[1][0]);
    acc1[1][1] = __builtin_elementwise_fma(B1, w1, acc1[1][1]);
    acc2[1][0] = __builtin_elementwise_fma(A1, w0, acc2[1][0]);
    acc2[1][1] = __builtin_elementwise_fma(A1, w1, acc2[1][1]);
  }
  // pos rows 128..135 (same multiplier both routings)
  #pragma unroll 2
  for (int i = 0; i < 8; i++) {
    float p0 = SB[PO + sp * 9 + i];
    float p1 = SB[PO + (sp + 32) * 9 + i];
    const v4f* w = (const v4f*)(Wg + (128 + i) * 64);
    v4f w0 = w[0], w1 = w[1];
    v4f P0 = {p0, p0, p0, p0}, P1 = {p1, p1, p1, p1};
    acc1[0][0] = __builtin_elementwise_fma(P0, w0, acc1[0][0]);
    acc1[0][1] = __builtin_elementwise_fma(P0, w1, acc1[0][1]);
    acc2[0][0] = __builtin_elementwise_fma(P0, w0, acc2[0][0]);
    acc2[0][1] = __builtin_elementwise_fma(P0, w1, acc2[0][1]);
    acc1[1][0] = __builtin_elementwise_fma(P1, w0, acc1[1][0]);
    acc1[1][1] = __builtin_elementwise_fma(P1, w1, acc1[1][1]);
    acc2[1][0] = __builtin_elementwise_fma(P1, w0, acc2[1][0]);
    acc2[1][1] = __builtin_elementwise_fma(P1, w1, acc2[1][1]);
  }
  // gelu in place
  #pragma unroll
  for (int s = 0; s < 2; s++)
    #pragma unroll
    for (int e = 0; e < 2; e++)
      #pragma unroll
      for (int c = 0; c < 4; c++) {
        acc1[s][e][c] = gelu_f(acc1[s][e][c]);
        acc2[s][e][c] = gelu_f(acc2[s][e][c]);
      }
  __syncthreads();   // all X/P reads done before HX overlays the X region
  // HX float2 [s][j] stride 66: (h1,h2) pairs
  float2* HX2 = (float2*)SB;
  #pragma unroll
  for (int s = 0; s < 2; s++) {
    int sg = sp + s * 32;
    #pragma unroll
    for (int e = 0; e < 2; e++)
      #pragma unroll
      for (int c = 0; c < 4; c++)
        HX2[sg * 66 + jg * 8 + e * 4 + c] = float2{acc1[s][e][c], acc2[s][e][c]};
  }
  __syncthreads();
  // layer 2: thread = (sample sL, output m); j ascending (exact round-0 sequence)
  int sL = tid >> 2, m = tid & 3;
  float l1 = RW[141 * 64 + m], l2 = l1;
  #pragma unroll 8
  for (int j = 0; j < 64; j++) {
    float2 h = HX2[sL * 66 + j];
    float wv = RW[137 * 64 + j * 4 + m];   // global, L1-hot
    l1 = fmaf(h.x, wv, l1);
    l2 = fmaf(h.y, wv, l2);
  }
  // quad argmax (strict >, lowest index wins) via DPP pair/half swaps
  float o1 = QP_F(l1, 0xB1), o2 = QP_F(l2, 0xB1);
  bool odd = (m & 1) != 0;
  float vhi1 = odd ? l1 : o1, vlo1 = odd ? o1 : l1;
  float vhi2 = odd ? l2 : o2, vlo2 = odd ? o2 : l2;
  int ihi = m | 1, ilo = m & ~1;
  bool w1c = vhi1 > vlo1, w2c = vhi2 > vlo2;
  float bv1 = w1c ? vhi1 : vlo1;  int bi1 = w1c ? ihi : ilo;
  float bv2 = w2c ? vhi2 : vlo2;  int bi2 = w2c ? ihi : ilo;
  float p1s = QP_F(bv1, 0x4E); int q1s = QP_I(bi1, 0x4E);
  float p2s = QP_F(bv2, 0x4E); int q2s = QP_I(bi2, 0x4E);
  bool hi2 = (m & 2) != 0;
  float uhi1 = hi2 ? bv1 : p1s, ulo1 = hi2 ? p1s : bv1;
  int   jhi1 = hi2 ? bi1 : q1s, jlo1 = hi2 ? q1s : bi1;
  float uhi2 = hi2 ? bv2 : p2s, ulo2 = hi2 ? p2s : bv2;
  int   jhi2 = hi2 ? bi2 : q2s, jlo2 = hi2 ? q2s : bi2;
  int idx1 = (uhi1 > ulo1) ? jhi1 : jlo1;
  int idx2 = (uhi2 > ulo2) ? jhi2 : jlo2;
  if (m == 0) {
    r1[s0 + sL] = (unsigned char)idx1;
    r2[s0 + sL] = (unsigned char)idx2;
    atomicAdd(&hcnt[idx1], 1u);
    atomicAdd(&hcnt[idx2], 1u);
  }
  __syncthreads();
  if (tid < 4) atomicAdd(gcounts + tid, hcnt[tid]);
}

// ---------------- K2b: padded bucket offsets + sentinel fill ----------------
// table[t] = padded start of bucket t (multiples of 128), table[4] = padded total.
__global__ __launch_bounds__(256) void offsets_k(
    const unsigned int* __restrict__ counts, unsigned int* __restrict__ table,
    unsigned int* __restrict__ cursors, unsigned int* __restrict__ list) {
  __shared__ unsigned int ps[5], cnt[4];
  int tid = threadIdx.x;
  if (tid == 0) {
    unsigned int acc = 0;
    for (int t = 0; t < 4; t++) {
      ps[t] = acc;
      unsigned int c = counts[t];
      cnt[t] = c;
      acc += ((c + 127u) >> 7) << 7;
    }
    ps[4] = acc;
    #pragma unroll
    for (int t = 0; t < 5; t++) table[t] = ps[t];
    #pragma unroll
    for (int t = 0; t < 4; t++) cursors[t] = ps[t];
  }
  __syncthreads();
  #pragma unroll
  for (int r = 0; r < 2; r++) {
    int idx = r * 256 + tid;
    int t = idx >> 7, i = idx & 127;
    unsigned int pos = ps[t] + cnt[t] + (unsigned int)i;
    if (pos < ps[t + 1]) list[pos] = 0xFFFFFFFFu;   // sentinel pad
  }
}

// ---------------- K2c: scatter pairs into bucketed list ----------------
// entry = (s << 1) | rb ; rb=0 -> out1 (expert r1[s]), rb=1 -> out2 (expert r2[s])
__global__ __launch_bounds__(256) void place_k(
    const unsigned char* __restrict__ r1, const unsigned char* __restrict__ r2,
    unsigned int* __restrict__ cursors, unsigned int* __restrict__ list) {
  __shared__ unsigned int lc[4], lb[4];
  int tid = threadIdx.x;
  if (tid < 4) lc[tid] = 0u;
  __syncthreads();
  int s = blockIdx.x * 256 + tid;
  int e1 = (int)r1[s], e2 = (int)r2[s];
  unsigned int k1 = atomicAdd(&lc[e1], 1u);
  unsigned int k2 = atomicAdd(&lc[e2], 1u);
  __syncthreads();
  if (tid < 4) lb[tid] = atomicAdd(&cursors[tid], lc[tid]);
  __syncthreads();
  list[lb[e1] + k1] = ((unsigned int)s << 1);
  list[lb[e2] + k2] = ((unsigned int)s << 1) | 1u;
}

// ---------------- K3: routed experts — ONE expert per block, 128 pairs ----------
// Same MFMA/gelu/bpermute arithmetic as the round-0 expert2_k (bit-identical for
// the selected expert); only the discarded 3 experts' work is eliminated.
__global__ __launch_bounds__(256) void expert3_k(
    const float* __restrict__ a, const float* __restrict__ b,
    const short* __restrict__ W1s, const short* __restrict__ W2s,
    const float* __restrict__ b1, const float* __restrict__ b2,
    const unsigned int* __restrict__ table, const unsigned int* __restrict__ list,
    float* __restrict__ out) {
  __shared__ short LB[24576];       // 48KB; overlaid: pair-frag staging then weights
  __shared__ unsigned int eLS[128];
  int tid = threadIdx.x;
  int wave = tid >> 6, lane = tid & 63;
  int q = lane >> 4, sm = lane & 15;

  unsigned int p0 = blockIdx.x * 128u;
  unsigned int t1 = table[1], t2 = table[2], t3 = table[3], t4 = table[4];
  if (p0 >= t4) return;             // uniform early-exit (no barriers yet)
  int t = (p0 >= t1) + (p0 >= t2) + (p0 >= t3);   // bucket = expert id

  if (tid < 128) eLS[tid] = list[p0 + tid];
  __syncthreads();

  // stage pair^T B-fragments for both 64-pair groups (lane-linear 16B slots)
  #pragma unroll
  for (int r = 0; r < 8; r++) {
    int slot = r * 256 + tid;                 // 2048 slots
    int g = slot >> 10, sg = slot & 1023;
    int f = sg >> 6, l = sg & 63;
    int sgrp = f >> 2, kb = f & 3;
    int ls2 = g * 64 + sgrp * 16 + (l & 15);
    unsigned int e = eLS[ls2];
    int s = (e == 0xFFFFFFFFu) ? 0 : (int)(e >> 1);
    int k = kb * 32 + (l >> 4) * 8;
    const float* src = (k < 64) ? (a + (size_t)s * 64 + k) : (b + (size_t)s * 64 + (k - 64));
    acc_t v0 = *(const acc_t*)(src);
    acc_t v1 = *(const acc_t*)(src + 4);
    i32x4_t pk;
    pk[0] = (int)pk2bf(v0[0], v0[1]);
    pk[1] = (int)pk2bf(v0[2], v0[3]);
    pk[2] = (int)pk2bf(v1[0], v1[1]);
    pk[3] = (int)pk2bf(v1[2], v1[3]);
    *(i32x4_t*)(&LB[slot * 8]) = pk;
  }
  __syncthreads();
  bfrag_t bfrag[2][4];
  #pragma unroll
  for (int g = 0; g < 2; g++)
    #pragma unroll
    for (int kb = 0; kb < 4; kb++)
      bfrag[g][kb] = *(const bfrag_t*)(&LB[((g * 16 + wave * 4 + kb) * 64 + lane) * 8]);

  unsigned int eA = eLS[wave * 16 + sm];
  unsigned int eB = eLS[64 + wave * 16 + sm];
  __syncthreads();   // all frag reads done before weights overwrite LB

  acc_t zero = {0.f, 0.f, 0.f, 0.f};
  int vb[4];
  #pragma unroll
  for (int kb = 0; kb < 4; kb++) vb[kb] = sm * 256 + (((kb * 4 + q) ^ sm) * 16);
  int addr0 = (((q & 1) * 2) * 16 + sm) * 4;
  int addr1 = addr0 + 64;
  bool hi = (q >> 1) != 0;

  // stage expert t's weights: W1s 32KB (2048 chunks) + W2s 16KB (1024 chunks)
  #pragma unroll
  for (int it = 0; it < 12; it++) {
    int cb = it * 256 + wave * 64;          // wave-uniform base
    int chunk = cb + lane;
    const short* gsrc = (chunk < 2048) ? (W1s + t * 16384 + chunk * 8)
                                       : (W2s + t * 8192 + (chunk - 2048) * 8);
    gload_lds16(gsrc, (char*)LB + cb * 16);
  }
  __syncthreads();

  #pragma unroll
  for (int g = 0; g < 2; g++) {
    // layer 1: h^T
    unsigned int hp[8][2];
    #pragma unroll
    for (int mt = 0; mt < 8; mt++) {
      acc_t c = zero;
      #pragma unroll
      for (int kb = 0; kb < 4; kb++) {
        bfrag_t A = *(const bfrag_t*)((const char*)LB + mt * 4096 + vb[kb]);
        c = __builtin_amdgcn_mfma_f32_16x16x32_bf16(A, bfrag[g][kb], c, 0, 0, 0);
      }
      acc_t bv = *(const acc_t*)(b1 + t * 128 + mt * 16 + q * 4);
      float g0 = gelu_f(c[0] + bv[0]);
      float g1 = gelu_f(c[1] + bv[1]);
      float g2 = gelu_f(c[2] + bv[2]);
      float g3 = gelu_f(c[3] + bv[3]);
      hp[mt][0] = pk2bf(g0, g1);
      hp[mt][1] = pk2bf(g2, g3);
    }
    // redistribute h^T C-frags -> layer-2 B-frags (wave-local bpermute)
    bfrag_t b2f[4];
    #pragma unroll
    for (int kb2 = 0; kb2 < 4; kb2++) {
      int p00 = __builtin_amdgcn_ds_bpermute(addr0, (int)hp[2 * kb2][0]);
      int p01 = __builtin_amdgcn_ds_bpermute(addr0, (int)hp[2 * kb2][1]);
      int p10 = __builtin_amdgcn_ds_bpermute(addr1, (int)hp[2 * kb2][0]);
      int p11 = __builtin_amdgcn_ds_bpermute(addr1, (int)hp[2 * kb2][1]);
      int q00 = __builtin_amdgcn_ds_bpermute(addr0, (int)hp[2 * kb2 + 1][0]);
      int q01 = __builtin_amdgcn_ds_bpermute(addr0, (int)hp[2 * kb2 + 1][1]);
      int q10 = __builtin_amdgcn_ds_bpermute(addr1, (int)hp[2 * kb2 + 1][0]);
      int q11 = __builtin_amdgcn_ds_bpermute(addr1, (int)hp[2 * kb2 + 1][1]);
      i32x4_t w;
      w[0] = hi ? q00 : p00;
      w[1] = hi ? q01 : p01;
      w[2] = hi ? q10 : p10;
      w[3] = hi ? q11 : p11;
      b2f[kb2] = __builtin_bit_cast(bfrag_t, w);
    }
    // layer 2 + guarded routed store
    unsigned int e = g ? eB : eA;
    bool live = (e != 0xFFFFFFFFu);
    size_t so = ((size_t)(e & 1u)) * B_N + (size_t)(e >> 1);
    float* p = out + so * 64 + q * 4;
    #pragma unroll
    for (int mt2 = 0; mt2 < 4; mt2++) {
      acc_t c = zero;
      #pragma unroll
      for (int kb2 = 0; kb2 < 4; kb2++) {
        bfrag_t A = *(const bfrag_t*)((const char*)LB + 32768 + mt2 * 4096 + vb[kb2]);
        c = __builtin_amdgcn_mfma_f32_16x16x32_bf16(A, b2f[kb2], c, 0, 0, 0);
      }
      acc_t bv = *(const acc_t*)(b2 + t * 64 + mt2 * 16 + q * 4);
      c[0] += bv[0]; c[1] += bv[1]; c[2] += bv[2]; c[3] += bv[3];
      if (live) *(acc_t*)(p + mt2 * 16) = c;
    }
  }
}

extern "C" void kernel_launch(void* const* d_in, const int* in_sizes, int n_in,
                              void* d_out, int out_size, void* d_ws, size_t ws_size,
                              hipStream_t stream) {
  const float* a   = (const float*)d_in[0];
  const float* bv  = (const float*)d_in[1];
  const float* pos = (const float*)d_in[2];
  const float* Wr1 = (const float*)d_in[3];
  const float* br1 = (const float*)d_in[4];
  const float* Wr2 = (const float*)d_in[5];
  const float* br2 = (const float*)d_in[6];
  const float* W1  = (const float*)d_in[7];
  const float* b1  = (const float*)d_in[8];
  const float* W2  = (const float*)d_in[9];
  const float* b2  = (const float*)d_in[10];
  float* out = (float*)d_out;

  // ws layout (BYTES):
  // r1 [0,131072) r2 [131072,262144) RW [262144,298496)
  // W1s [298496,429568) W2s [429568,495104)
  // counts [495104,495120) cursors [495120,495136) table [495136,495156)
  // list [495168, 495168+1050608) -- 262144 pairs + <=508 pad sentinels
  unsigned char* r1 = (unsigned char*)d_ws;
  unsigned char* r2 = r1 + B_N;
  float* RW  = (float*)((char*)d_ws + 262144);
  short* W1s = (short*)((char*)d_ws + 298496);
  short* W2s = (short*)((char*)d_ws + 429568);
  unsigned int* counts  = (unsigned int*)((char*)d_ws + 495104);
  unsigned int* cursors = (unsigned int*)((char*)d_ws + 495120);
  unsigned int* table   = (unsigned int*)((char*)d_ws + 495136);
  unsigned int* list    = (unsigned int*)((char*)d_ws + 495168);

  prepack2_k<<<64, 256, 0, stream>>>(Wr1, br1, Wr2, br2, W1, W2, RW, W1s, W2s, counts);
  router12_k<<<B_N / 64, 256, 0, stream>>>(a, bv, pos, RW, r1, r2, counts);
  offsets_k<<<1, 256, 0, stream>>>(counts, table, cursors, list);
  place_k<<<B_N / 256, 256, 0, stream>>>(r1, r2, cursors, list);
  expert3_k<<<2052, 256, 0, stream>>>(a, bv, W1s, W2s, b1, b2, table, list, out);
}

// Round 9
// 247.954 us; speedup vs baseline: 1.0537x; 1.0537x over previous
//
#include <hip/hip_runtime.h>

#define B_N 131072

using bfrag_t = __attribute__((ext_vector_type(8))) short;  // 8 bf16 (MFMA A/B frag)
using acc_t   = __attribute__((ext_vector_type(4))) float;  // 4 fp32 (MFMA C/D frag)
using v4f     = __attribute__((ext_vector_type(4))) float;
using i32x4_t = __attribute__((ext_vector_type(4))) int;

__device__ __forceinline__ unsigned short f2bf(float f) {
  unsigned int u = __float_as_uint(f);
  u += 0x7FFFu + ((u >> 16) & 1u);   // RNE
  return (unsigned short)(u >> 16);
}

__device__ __forceinline__ unsigned int pk2bf(float x, float y) {
  return (unsigned int)f2bf(x) | ((unsigned int)f2bf(y) << 16);
}

// async global->LDS, 16B per lane; lds base must be wave-uniform (lane-linear dest)
__device__ __forceinline__ void gload_lds16(const void* g, void* l) {
  __builtin_amdgcn_global_load_lds((const __attribute__((address_space(1))) void*)g,
                                   (__attribute__((address_space(3))) void*)l, 16, 0, 0);
}

// exact GELU: 0.5x(1+erf(x/sqrt2)); erf via Abramowitz-Stegun 7.1.26, |eps|<=1.5e-7
__device__ __forceinline__ float gelu_f(float x) {
  float ax = fabsf(x) * 0.70710678118654752f;
  float t  = __builtin_amdgcn_rcpf(fmaf(0.3275911f, ax, 1.0f));
  float p  = fmaf(1.061405429f, t, -1.453152027f);
  p = fmaf(p, t, 1.421413741f);
  p = fmaf(p, t, -0.284496736f);
  p = fmaf(p, t, 0.254829592f);
  p = p * t;
  float e  = __expf(-ax * ax);
  float er = fmaf(-p, e, 1.0f);
  er = (x < 0.0f) ? -er : er;
  return 0.5f * x * (1.0f + er);
}

// quad_perm DPP (compile-time ctrl): [1,0,3,2]=0xB1 pair-swap, [2,3,0,1]=0x4E half-swap
#define QP_F(v, CTRL) __int_as_float(__builtin_amdgcn_mov_dpp(__float_as_int(v), (CTRL), 0xF, 0xF, false))
#define QP_I(v, CTRL) __builtin_amdgcn_mov_dpp((v), (CTRL), 0xF, 0xF, false)

// ---------------- K1: prepack (round-0 version + counter/cursor zeroing) --------
__global__ __launch_bounds__(256) void prepack2_k(
    const float* __restrict__ Wr1, const float* __restrict__ br1,
    const float* __restrict__ Wr2, const float* __restrict__ br2,
    const float* __restrict__ W1, const float* __restrict__ W2,
    float* __restrict__ RW, short* __restrict__ W1s, short* __restrict__ W2s,
    unsigned int* __restrict__ counts, unsigned int* __restrict__ cursors) {
  int gt = blockIdx.x * 256 + threadIdx.x;   // grid 64 -> 16384 threads
  if (gt < 4) counts[gt] = 0u;
  else if (gt < 8) cursors[gt - 4] = 0u;
  for (int idx = gt; idx < 142 * 64; idx += 16384) {
    int row = idx >> 6, j = idx & 63; float val;
    if (row < 136)      val = Wr1[row * 64 + j];
    else if (row == 136) val = br1[j];
    else if (row < 141) val = Wr2[(row - 137) * 64 + j];
    else                val = (j < 4) ? br2[j] : 0.0f;
    RW[idx] = val;
  }
  for (int ch = gt; ch < 8192; ch += 16384) {  // W1: (4,128,128) [t][k][n]
    int t = ch >> 11, r = (ch >> 4) & 127, c = ch & 15;
    const float* src = W1 + t * 16384 + r;     // stride 128 over k
    short* dst = W1s + (t * 128 + r) * 128 + ((c ^ (r & 15)) * 8);
    #pragma unroll
    for (int m = 0; m < 8; m++) dst[m] = (short)f2bf(src[(c * 8 + m) * 128]);
  }
  for (int ch = gt; ch < 4096; ch += 16384) {  // W2: (4,128,64) [t][k][d]
    int t = ch >> 10, d = (ch >> 4) & 63, c = ch & 15;
    const float* src = W2 + t * 8192 + d;      // stride 64 over k
    short* dst = W2s + (t * 64 + d) * 128 + ((c ^ (d & 15)) * 8);
    #pragma unroll
    for (int m = 0; m < 8; m++) dst[m] = (short)f2bf(src[(c * 8 + m) * 64]);
  }
}

// ---------------- K2: router v11b = round-6 v11 + bf16 pair prepack store -------
// Compute path IDENTICAL to round-6 router11 (84us, argmax-safe). Added: during
// the coalesced X staging, pack pair rows to bf16 (same f2bf RNE as expert input
// conversion -> bit-identical fragments) and store 256B/sample to pairs16.
// ROUND-8 BUG FIXED: X staging dst was missing the XO offset (X overwrote the WB
// weight rows in LDS -> garbage routing). dst = SB + XO + s*130 + k.
__global__ __launch_bounds__(256) void router11b_k(
    const float* __restrict__ a, const float* __restrict__ b,
    const float* __restrict__ pos, const float* __restrict__ RW,
    unsigned char* __restrict__ r1, unsigned char* __restrict__ r2,
    unsigned int* __restrict__ gcounts, unsigned short* __restrict__ pairs16,
    int dopack) {
  __shared__ float SB[17984];   // WB [0,9088) | X [9088,17408) s*130 (a|b) | P [17408,17984) s*9
  __shared__ unsigned int hcnt[4];
  const int XO = 9088, PO = 17408;
  int tid = threadIdx.x, wave = tid >> 6, lane = tid & 63;
  int s0 = blockIdx.x * 64;
  if (tid < 4) hcnt[tid] = 0u;

  // WB: rows 0-135 Wr1, 136 br1, 137-140 Wr2 flat, 141 br2 (2272 16B chunks)
  for (int it = 0; it < 9; it++) {
    int cb = it * 256 + wave * 64;       // wave-uniform lds base
    if (cb < 2272) {
      int chunk = cb + lane;
      if (chunk < 2272) gload_lds16(RW + chunk * 4, (char*)SB + cb * 16);
    }
  }
  // X natural: X[s][0..63]=a, [64..127]=b ; stride 130 (float2-aligned stores)
  // + bf16 pair pack to global (fills idle VALU/VMEM slots of LDS-bound kernel)
  #pragma unroll
  for (int it = 0; it < 8; it++) {
    int idx = it * 256 + tid;            // 2048 v4f chunks = 64 samples x 32
    int s = idx >> 5, c = idx & 31;
    const float* src = (c < 16) ? (a + (size_t)(s0 + s) * 64 + c * 4)
                                : (b + (size_t)(s0 + s) * 64 + (c - 16) * 4);
    v4f v = *(const v4f*)src;
    int k = (c < 16) ? c * 4 : 64 + (c - 16) * 4;   // global pair index
    float* dst = SB + XO + s * 130 + k;             // <-- XO fix
    *(float2*)dst = float2{v[0], v[1]};
    *(float2*)(dst + 2) = float2{v[2], v[3]};
    if (dopack) {
      uint2 pk;
      pk.x = pk2bf(v[0], v[1]);
      pk.y = pk2bf(v[2], v[3]);
      *(uint2*)((char*)pairs16 + ((size_t)(s0 + s) * 128 + k) * 2) = pk;
    }
  }
  // P[s][c], stride 9
  #pragma unroll
  for (int r = 0; r < 2; r++) {
    int idx = r * 256 + tid;             // 512 = 64 samples x 8
    int s = idx >> 3, c = idx & 7;
    SB[PO + s * 9 + c] = pos[(size_t)(s0 + s) * 8 + c];
  }
  __syncthreads();

  int sp = tid >> 3, jg = tid & 7;       // samples {sp, sp+32}; channels jg*8..+7
  const float* Xs0 = SB + XO + sp * 130;
  const float* Xs1 = SB + XO + (sp + 32) * 130;
  v4f acc1[2][2], acc2[2][2];            // [sample][v4f-half of 8 channels]
  {
    v4f bi0 = *(const v4f*)(SB + 136 * 64 + jg * 8);
    v4f bi1 = *(const v4f*)(SB + 136 * 64 + jg * 8 + 4);
    acc1[0][0] = bi0; acc1[0][1] = bi1; acc1[1][0] = bi0; acc1[1][1] = bi1;
    acc2[0][0] = bi0; acc2[0][1] = bi1; acc2[1][0] = bi0; acc2[1][1] = bi1;
  }
  // rows 0..63: acc1 += a_i*W[i], acc2 += b_i*W[i]  (i ascending)
  #pragma unroll 4
  for (int i = 0; i < 64; i++) {
    float xa0 = Xs0[i], xb0 = Xs0[64 + i];     // one ds_read2_b32
    float xa1 = Xs1[i], xb1 = Xs1[64 + i];     // one ds_read2_b32
    const v4f* w = (const v4f*)(SB + i * 64 + jg * 8);
    v4f w0 = w[0], w1 = w[1];
    v4f A0 = {xa0, xa0, xa0, xa0}, B0 = {xb0, xb0, xb0, xb0};
    v4f A1 = {xa1, xa1, xa1, xa1}, B1 = {xb1, xb1, xb1, xb1};
    acc1[0][0] = __builtin_elementwise_fma(A0, w0, acc1[0][0]);
    acc1[0][1] = __builtin_elementwise_fma(A0, w1, acc1[0][1]);
    acc2[0][0] = __builtin_elementwise_fma(B0, w0, acc2[0][0]);
    acc2[0][1] = __builtin_elementwise_fma(B0, w1, acc2[0][1]);
    acc1[1][0] = __builtin_elementwise_fma(A1, w0, acc1[1][0]);
    acc1[1][1] = __builtin_elementwise_fma(A1, w1, acc1[1][1]);
    acc2[1][0] = __builtin_elementwise_fma(B1, w0, acc2[1][0]);
    acc2[1][1] = __builtin_elementwise_fma(B1, w1, acc2[1][1]);
  }
  // rows 64..127: acc1 += b_i*W[64+i], acc2 += a_i*W[64+i]
  #pragma unroll 4
  for (int i = 0; i < 64; i++) {
    float xa0 = Xs0[i], xb0 = Xs0[64 + i];
    float xa1 = Xs1[i], xb1 = Xs1[64 + i];
    const v4f* w = (const v4f*)(SB + (64 + i) * 64 + jg * 8);
    v4f w0 = w[0], w1 = w[1];
    v4f A0 = {xa0, xa0, xa0, xa0}, B0 = {xb0, xb0, xb0, xb0};
    v4f A1 = {xa1, xa1, xa1, xa1}, B1 = {xb1, xb1, xb1, xb1};
    acc1[0][0] = __builtin_elementwise_fma(B0, w0, acc1[0][0]);
    acc1[0][1] = __builtin_elementwise_fma(B0, w1, acc1[0][1]);
    acc2[0][0] = __builtin_elementwise_fma(A0, w0, acc2[0][0]);
    acc2[0][1] = __builtin_elementwise_fma(A0, w1, acc2[0][1]);
    acc1[1][0] = __builtin_elementwise_fma(B1, w0, acc1[1][0]);
    acc1[1][1] = __builtin_elementwise_fma(B1, w1, acc1[1][1]);
    acc2[1][0] = __builtin_elementwise_fma(A1, w0, acc2[1][0]);
    acc2[1][1] = __builtin_elementwise_fma(A1, w1, acc2[1][1]);
  }
  // pos rows 128..135 (same multiplier both routings)
  #pragma unroll 2
  for (int i = 0; i < 8; i++) {
    float p0 = SB[PO + sp * 9 + i];
    float p1 = SB[PO + (sp + 32) * 9 + i];
    const v4f* w = (const v4f*)(SB + (128 + i) * 64 + jg * 8);
    v4f w0 = w[0], w1 = w[1];
    v4f P0 = {p0, p0, p0, p0}, P1 = {p1, p1, p1, p1};
    acc1[0][0] = __builtin_elementwise_fma(P0, w0, acc1[0][0]);
    acc1[0][1] = __builtin_elementwise_fma(P0, w1, acc1[0][1]);
    acc2[0][0] = __builtin_elementwise_fma(P0, w0, acc2[0][0]);
    acc2[0][1] = __builtin_elementwise_fma(P0, w1, acc2[0][1]);
    acc1[1][0] = __builtin_elementwise_fma(P1, w0, acc1[1][0]);
    acc1[1][1] = __builtin_elementwise_fma(P1, w1, acc1[1][1]);
    acc2[1][0] = __builtin_elementwise_fma(P1, w0, acc2[1][0]);
    acc2[1][1] = __builtin_elementwise_fma(P1, w1, acc2[1][1]);
  }
  // gelu in place
  #pragma unroll
  for (int s = 0; s < 2; s++)
    #pragma unroll
    for (int e = 0; e < 2; e++)
      #pragma unroll
      for (int c = 0; c < 4; c++) {
        acc1[s][e][c] = gelu_f(acc1[s][e][c]);
        acc2[s][e][c] = gelu_f(acc2[s][e][c]);
      }
  __syncthreads();   // all X/P reads done before HX overlays the X region
  // HX float2 [s][j] stride 66: (h1,h2) pairs
  float2* HX2 = (float2*)(SB + XO);
  #pragma unroll
  for (int s = 0; s < 2; s++) {
    int sg = sp + s * 32;
    #pragma unroll
    for (int e = 0; e < 2; e++)
      #pragma unroll
      for (int c = 0; c < 4; c++)
        HX2[sg * 66 + jg * 8 + e * 4 + c] = float2{acc1[s][e][c], acc2[s][e][c]};
  }
  __syncthreads();
  // layer 2: thread = (sample sL, output m); j ascending (exact round-0 sequence)
  int sL = tid >> 2, m = tid & 3;
  float l1 = SB[141 * 64 + m], l2 = l1;
  #pragma unroll 8
  for (int j = 0; j < 64; j++) {
    float2 h = HX2[sL * 66 + j];
    float wv = SB[137 * 64 + j * 4 + m];
    l1 = fmaf(h.x, wv, l1);
    l2 = fmaf(h.y, wv, l2);
  }
  // quad argmax (strict >, lowest index wins) via DPP pair/half swaps
  float o1 = QP_F(l1, 0xB1), o2 = QP_F(l2, 0xB1);
  bool odd = (m & 1) != 0;
  float vhi1 = odd ? l1 : o1, vlo1 = odd ? o1 : l1;
  float vhi2 = odd ? l2 : o2, vlo2 = odd ? o2 : l2;
  int ihi = m | 1, ilo = m & ~1;
  bool w1c = vhi1 > vlo1, w2c = vhi2 > vlo2;
  float bv1 = w1c ? vhi1 : vlo1;  int bi1 = w1c ? ihi : ilo;
  float bv2 = w2c ? vhi2 : vlo2;  int bi2 = w2c ? ihi : ilo;
  float p1s = QP_F(bv1, 0x4E); int q1s = QP_I(bi1, 0x4E);
  float p2s = QP_F(bv2, 0x4E); int q2s = QP_I(bi2, 0x4E);
  bool hi2 = (m & 2) != 0;
  float uhi1 = hi2 ? bv1 : p1s, ulo1 = hi2 ? p1s : bv1;
  int   jhi1 = hi2 ? bi1 : q1s, jlo1 = hi2 ? q1s : bi1;
  float uhi2 = hi2 ? bv2 : p2s, ulo2 = hi2 ? p2s : bv2;
  int   jhi2 = hi2 ? bi2 : q2s, jlo2 = hi2 ? q2s : bi2;
  int idx1 = (uhi1 > ulo1) ? jhi1 : jlo1;
  int idx2 = (uhi2 > ulo2) ? jhi2 : jlo2;
  if (m == 0) {
    r1[s0 + sL] = (unsigned char)idx1;
    r2[s0 + sL] = (unsigned char)idx2;
    atomicAdd(&hcnt[idx1], 1u);
    atomicAdd(&hcnt[idx2], 1u);
  }
  __syncthreads();
  if (tid < 4) atomicAdd(gcounts + tid, hcnt[tid]);
}

// ---------------- K2c': place2 — offsets fused in (cursors start at 0) ----------
// Every block derives the padded prefix ps[] from counts; blocks 0-3 also write
// the <=127 sentinel pads for their bucket (disjoint from entry region, no race).
__global__ __launch_bounds__(256) void place2_k(
    const unsigned char* __restrict__ r1, const unsigned char* __restrict__ r2,
    const unsigned int* __restrict__ counts, unsigned int* __restrict__ cursors,
    unsigned int* __restrict__ list) {
  __shared__ unsigned int lc[4], lb[4], psS[5];
  int tid = threadIdx.x;
  if (tid == 0) {
    unsigned int acc = 0;
    #pragma unroll
    for (int t = 0; t < 4; t++) {
      psS[t] = acc;
      acc += ((counts[t] + 127u) >> 7) << 7;
    }
    psS[4] = acc;
  }
  if (tid < 4) lc[tid] = 0u;
  __syncthreads();
  int s = blockIdx.x * 256 + tid;
  int e1 = (int)r1[s], e2 = (int)r2[s];
  unsigned int k1 = atomicAdd(&lc[e1], 1u);
  unsigned int k2 = atomicAdd(&lc[e2], 1u);
  __syncthreads();
  if (tid < 4) lb[tid] = atomicAdd(&cursors[tid], lc[tid]);
  __syncthreads();
  list[psS[e1] + lb[e1] + k1] = ((unsigned int)s << 1);
  list[psS[e2] + lb[e2] + k2] = ((unsigned int)s << 1) | 1u;
  if (blockIdx.x < 4) {
    int t = blockIdx.x;
    unsigned int cnt = counts[t];
    unsigned int pad = psS[t + 1] - psS[t] - cnt;
    if ((unsigned int)tid < pad) list[psS[t] + cnt + tid] = 0xFFFFFFFFu;
  }
}

// ---------------- K3': expert4 — pairs16 gload staging (zero staging VALU) ------
__global__ __launch_bounds__(256) void expert4_k(
    const unsigned short* __restrict__ pairs16,
    const short* __restrict__ W1s, const short* __restrict__ W2s,
    const float* __restrict__ b1, const float* __restrict__ b2,
    const unsigned int* __restrict__ counts, const unsigned int* __restrict__ list,
    float* __restrict__ out) {
  __shared__ short LB[24576];       // 48KB; overlaid: pair-frag staging then weights
  __shared__ unsigned int eLS[128];
  int tid = threadIdx.x;
  int wave = tid >> 6, lane = tid & 63;
  int q = lane >> 4, sm = lane & 15;

  // derive padded prefix from counts (uniform scalar loads)
  unsigned int c0 = counts[0], c1 = counts[1], c2 = counts[2], c3 = counts[3];
  unsigned int ps1 = (((c0 + 127u) >> 7) << 7);
  unsigned int ps2 = ps1 + (((c1 + 127u) >> 7) << 7);
  unsigned int ps3 = ps2 + (((c2 + 127u) >> 7) << 7);
  unsigned int ps4 = ps3 + (((c3 + 127u) >> 7) << 7);

  unsigned int p0 = blockIdx.x * 128u;
  if (p0 >= ps4) return;            // uniform early-exit (no barriers yet)
  int t = (p0 >= ps1) + (p0 >= ps2) + (p0 >= ps3);   // bucket = expert id

  if (tid < 128) eLS[tid] = list[p0 + tid];
  __syncthreads();

  // stage pair^T B-fragments via global_load_lds from pre-packed bf16 rows
  #pragma unroll
  for (int r = 0; r < 8; r++) {
    int cb = r * 256 + wave * 64;             // wave-uniform LDS base (slots)
    int slot = cb + lane;
    int g = slot >> 10, sg = slot & 1023;
    int f = sg >> 6, l = sg & 63;
    int sgrp = f >> 2, kb = f & 3;
    unsigned int e = eLS[g * 64 + sgrp * 16 + (l & 15)];
    int s = (e == 0xFFFFFFFFu) ? 0 : (int)(e >> 1);
    int k = kb * 32 + (l >> 4) * 8;
    gload_lds16((const char*)pairs16 + ((size_t)s * 128 + k) * 2,
                (char*)LB + cb * 16);
  }
  __syncthreads();
  bfrag_t bfrag[2][4];
  #pragma unroll
  for (int g = 0; g < 2; g++)
    #pragma unroll
    for (int kb = 0; kb < 4; kb++)
      bfrag[g][kb] = *(const bfrag_t*)(&LB[((g * 16 + wave * 4 + kb) * 64 + lane) * 8]);

  unsigned int eA = eLS[wave * 16 + sm];
  unsigned int eB = eLS[64 + wave * 16 + sm];
  __syncthreads();   // all frag reads done before weights overwrite LB

  acc_t zero = {0.f, 0.f, 0.f, 0.f};
  int vb[4];
  #pragma unroll
  for (int kb = 0; kb < 4; kb++) vb[kb] = sm * 256 + (((kb * 4 + q) ^ sm) * 16);
  int addr0 = (((q & 1) * 2) * 16 + sm) * 4;
  int addr1 = addr0 + 64;
  bool hi = (q >> 1) != 0;

  // stage expert t's weights: W1s 32KB (2048 chunks) + W2s 16KB (1024 chunks)
  #pragma unroll
  for (int it = 0; it < 12; it++) {
    int cb = it * 256 + wave * 64;          // wave-uniform base
    int chunk = cb + lane;
    const short* gsrc = (chunk < 2048) ? (W1s + t * 16384 + chunk * 8)
                                       : (W2s + t * 8192 + (chunk - 2048) * 8);
    gload_lds16(gsrc, (char*)LB + cb * 16);
  }
  __syncthreads();

  #pragma unroll
  for (int g = 0; g < 2; g++) {
    // layer 1: h^T
    unsigned int hp[8][2];
    #pragma unroll
    for (int mt = 0; mt < 8; mt++) {
      acc_t c = zero;
      #pragma unroll
      for (int kb = 0; kb < 4; kb++) {
        bfrag_t A = *(const bfrag_t*)((const char*)LB + mt * 4096 + vb[kb]);
        c = __builtin_amdgcn_mfma_f32_16x16x32_bf16(A, bfrag[g][kb], c, 0, 0, 0);
      }
      acc_t bv = *(const acc_t*)(b1 + t * 128 + mt * 16 + q * 4);
      float g0 = gelu_f(c[0] + bv[0]);
      float g1 = gelu_f(c[1] + bv[1]);
      float g2 = gelu_f(c[2] + bv[2]);
      float g3 = gelu_f(c[3] + bv[3]);
      hp[mt][0] = pk2bf(g0, g1);
      hp[mt][1] = pk2bf(g2, g3);
    }
    // redistribute h^T C-frags -> layer-2 B-frags (wave-local bpermute)
    bfrag_t b2f[4];
    #pragma unroll
    for (int kb2 = 0; kb2 < 4; kb2++) {
      int p00 = __builtin_amdgcn_ds_bpermute(addr0, (int)hp[2 * kb2][0]);
      int p01 = __builtin_amdgcn_ds_bpermute(addr0, (int)hp[2 * kb2][1]);
      int p10 = __builtin_amdgcn_ds_bpermute(addr1, (int)hp[2 * kb2][0]);
      int p11 = __builtin_amdgcn_ds_bpermute(addr1, (int)hp[2 * kb2][1]);
      int q00 = __builtin_amdgcn_ds_bpermute(addr0, (int)hp[2 * kb2 + 1][0]);
      int q01 = __builtin_amdgcn_ds_bpermute(addr0, (int)hp[2 * kb2 + 1][1]);
      int q10 = __builtin_amdgcn_ds_bpermute(addr1, (int)hp[2 * kb2 + 1][0]);
      int q11 = __builtin_amdgcn_ds_bpermute(addr1, (int)hp[2 * kb2 + 1][1]);
      i32x4_t w;
      w[0] = hi ? q00 : p00;
      w[1] = hi ? q01 : p01;
      w[2] = hi ? q10 : p10;
      w[3] = hi ? q11 : p11;
      b2f[kb2] = __builtin_bit_cast(bfrag_t, w);
    }
    // layer 2 + guarded routed store
    unsigned int e = g ? eB : eA;
    bool live = (e != 0xFFFFFFFFu);
    size_t so = ((size_t)(e & 1u)) * B_N + (size_t)(e >> 1);
    float* p = out + so * 64 + q * 4;
    #pragma unroll
    for (int mt2 = 0; mt2 < 4; mt2++) {
      acc_t c = zero;
      #pragma unroll
      for (int kb2 = 0; kb2 < 4; kb2++) {
        bfrag_t A = *(const bfrag_t*)((const char*)LB + 32768 + mt2 * 4096 + vb[kb2]);
        c = __builtin_amdgcn_mfma_f32_16x16x32_bf16(A, b2f[kb2], c, 0, 0, 0);
      }
      acc_t bv = *(const acc_t*)(b2 + t * 64 + mt2 * 16 + q * 4);
      c[0] += bv[0]; c[1] += bv[1]; c[2] += bv[2]; c[3] += bv[3];
      if (live) *(acc_t*)(p + mt2 * 16) = c;
    }
  }
}

// ============ FALLBACK PATH (round-6 proven kernels, used if ws too small) ======
__global__ __launch_bounds__(256) void offsets_k(
    const unsigned int* __restrict__ counts, unsigned int* __restrict__ table,
    unsigned int* __restrict__ cursors, unsigned int* __restrict__ list) {
  __shared__ unsigned int ps[5], cnt[4];
  int tid = threadIdx.x;
  if (tid == 0) {
    unsigned int acc = 0;
    for (int t = 0; t < 4; t++) {
      ps[t] = acc;
      unsigned int c = counts[t];
      cnt[t] = c;
      acc += ((c + 127u) >> 7) << 7;
    }
    ps[4] = acc;
    #pragma unroll
    for (int t = 0; t < 5; t++) table[t] = ps[t];
    #pragma unroll
    for (int t = 0; t < 4; t++) cursors[t] = ps[t];
  }
  __syncthreads();
  #pragma unroll
  for (int r = 0; r < 2; r++) {
    int idx = r * 256 + tid;
    int t = idx >> 7, i = idx & 127;
    unsigned int pos = ps[t] + cnt[t] + (unsigned int)i;
    if (pos < ps[t + 1]) list[pos] = 0xFFFFFFFFu;
  }
}

__global__ __launch_bounds__(256) void place_k(
    const unsigned char* __restrict__ r1, const unsigned char* __restrict__ r2,
    unsigned int* __restrict__ cursors, unsigned int* __restrict__ list) {
  __shared__ unsigned int lc[4], lb[4];
  int tid = threadIdx.x;
  if (tid < 4) lc[tid] = 0u;
  __syncthreads();
  int s = blockIdx.x * 256 + tid;
  int e1 = (int)r1[s], e2 = (int)r2[s];
  unsigned int k1 = atomicAdd(&lc[e1], 1u);
  unsigned int k2 = atomicAdd(&lc[e2], 1u);
  __syncthreads();
  if (tid < 4) lb[tid] = atomicAdd(&cursors[tid], lc[tid]);
  __syncthreads();
  list[lb[e1] + k1] = ((unsigned int)s << 1);
  list[lb[e2] + k2] = ((unsigned int)s << 1) | 1u;
}

__global__ __launch_bounds__(256) void expert3_k(
    const float* __restrict__ a, const float* __restrict__ b,
    const short* __restrict__ W1s, const short* __restrict__ W2s,
    const float* __restrict__ b1, const float* __restrict__ b2,
    const unsigned int* __restrict__ table, const unsigned int* __restrict__ list,
    float* __restrict__ out) {
  __shared__ short LB[24576];
  __shared__ unsigned int eLS[128];
  int tid = threadIdx.x;
  int wave = tid >> 6, lane = tid & 63;
  int q = lane >> 4, sm = lane & 15;

  unsigned int p0 = blockIdx.x * 128u;
  unsigned int t1 = table[1], t2 = table[2], t3 = table[3], t4 = table[4];
  if (p0 >= t4) return;
  int t = (p0 >= t1) + (p0 >= t2) + (p0 >= t3);

  if (tid < 128) eLS[tid] = list[p0 + tid];
  __syncthreads();

  #pragma unroll
  for (int r = 0; r < 8; r++) {
    int slot = r * 256 + tid;
    int g = slot >> 10, sg = slot & 1023;
    int f = sg >> 6, l = sg & 63;
    int sgrp = f >> 2, kb = f & 3;
    int ls2 = g * 64 + sgrp * 16 + (l & 15);
    unsigned int e = eLS[ls2];
    int s = (e == 0xFFFFFFFFu) ? 0 : (int)(e >> 1);
    int k = kb * 32 + (l >> 4) * 8;
    const float* src = (k < 64) ? (a + (size_t)s * 64 + k) : (b + (size_t)s * 64 + (k - 64));
    acc_t v0 = *(const acc_t*)(src);
    acc_t v1 = *(const acc_t*)(src + 4);
    i32x4_t pk;
    pk[0] = (int)pk2bf(v0[0], v0[1]);
    pk[1] = (int)pk2bf(v0[2], v0[3]);
    pk[2] = (int)pk2bf(v1[0], v1[1]);
    pk[3] = (int)pk2bf(v1[2], v1[3]);
    *(i32x4_t*)(&LB[slot * 8]) = pk;
  }
  __syncthreads();
  bfrag_t bfrag[2][4];
  #pragma unroll
  for (int g = 0; g < 2; g++)
    #pragma unroll
    for (int kb = 0; kb < 4; kb++)
      bfrag[g][kb] = *(const bfrag_t*)(&LB[((g * 16 + wave * 4 + kb) * 64 + lane) * 8]);

  unsigned int eA = eLS[wave * 16 + sm];
  unsigned int eB = eLS[64 + wave * 16 + sm];
  __syncthreads();

  acc_t zero = {0.f, 0.f, 0.f, 0.f};
  int vb[4];
  #pragma unroll
  for (int kb = 0; kb < 4; kb++) vb[kb] = sm * 256 + (((kb * 4 + q) ^ sm) * 16);
  int addr0 = (((q & 1) * 2) * 16 + sm) * 4;
  int addr1 = addr0 + 64;
  bool hi = (q >> 1) != 0;

  #pragma unroll
  for (int it = 0; it < 12; it++) {
    int cb = it * 256 + wave * 64;
    int chunk = cb + lane;
    const short* gsrc = (chunk < 2048) ? (W1s + t * 16384 + chunk * 8)
                                       : (W2s + t * 8192 + (chunk - 2048) * 8);
    gload_lds16(gsrc, (char*)LB + cb * 16);
  }
  __syncthreads();

  #pragma unroll
  for (int g = 0; g < 2; g++) {
    unsigned int hp[8][2];
    #pragma unroll
    for (int mt = 0; mt < 8; mt++) {
      acc_t c = zero;
      #pragma unroll
      for (int kb = 0; kb < 4; kb++) {
        bfrag_t A = *(const bfrag_t*)((const char*)LB + mt * 4096 + vb[kb]);
        c = __builtin_amdgcn_mfma_f32_16x16x32_bf16(A, bfrag[g][kb], c, 0, 0, 0);
      }
      acc_t bv = *(const acc_t*)(b1 + t * 128 + mt * 16 + q * 4);
      float g0 = gelu_f(c[0] + bv[0]);
      float g1 = gelu_f(c[1] + bv[1]);
      float g2 = gelu_f(c[2] + bv[2]);
      float g3 = gelu_f(c[3] + bv[3]);
      hp[mt][0] = pk2bf(g0, g1);
      hp[mt][1] = pk2bf(g2, g3);
    }
    bfrag_t b2f[4];
    #pragma unroll
    for (int kb2 = 0; kb2 < 4; kb2++) {
      int p00 = __builtin_amdgcn_ds_bpermute(addr0, (int)hp[2 * kb2][0]);
      int p01 = __builtin_amdgcn_ds_bpermute(addr0, (int)hp[2 * kb2][1]);
      int p10 = __builtin_amdgcn_ds_bpermute(addr1, (int)hp[2 * kb2][0]);
      int p11 = __builtin_amdgcn_ds_bpermute(addr1, (int)hp[2 * kb2][1]);
      int q00 = __builtin_amdgcn_ds_bpermute(addr0, (int)hp[2 * kb2 + 1][0]);
      int q01 = __builtin_amdgcn_ds_bpermute(addr0, (int)hp[2 * kb2 + 1][1]);
      int q10 = __builtin_amdgcn_ds_bpermute(addr1, (int)hp[2 * kb2 + 1][0]);
      int q11 = __builtin_amdgcn_ds_bpermute(addr1, (int)hp[2 * kb2 + 1][1]);
      i32x4_t w;
      w[0] = hi ? q00 : p00;
      w[1] = hi ? q01 : p01;
      w[2] = hi ? q10 : p10;
      w[3] = hi ? q11 : p11;
      b2f[kb2] = __builtin_bit_cast(bfrag_t, w);
    }
    unsigned int e = g ? eB : eA;
    bool live = (e != 0xFFFFFFFFu);
    size_t so = ((size_t)(e & 1u)) * B_N + (size_t)(e >> 1);
    float* p = out + so * 64 + q * 4;
    #pragma unroll
    for (int mt2 = 0; mt2 < 4; mt2++) {
      acc_t c = zero;
      #pragma unroll
      for (int kb2 = 0; kb2 < 4; kb2++) {
        bfrag_t A = *(const bfrag_t*)((const char*)LB + 32768 + mt2 * 4096 + vb[kb2]);
        c = __builtin_amdgcn_mfma_f32_16x16x32_bf16(A, b2f[kb2], c, 0, 0, 0);
      }
      acc_t bv = *(const acc_t*)(b2 + t * 64 + mt2 * 16 + q * 4);
      c[0] += bv[0]; c[1] += bv[1]; c[2] += bv[2]; c[3] += bv[3];
      if (live) *(acc_t*)(p + mt2 * 16) = c;
    }
  }
}

extern "C" void kernel_launch(void* const* d_in, const int* in_sizes, int n_in,
                              void* d_out, int out_size, void* d_ws, size_t ws_size,
                              hipStream_t stream) {
  const float* a   = (const float*)d_in[0];
  const float* bv  = (const float*)d_in[1];
  const float* pos = (const float*)d_in[2];
  const float* Wr1 = (const float*)d_in[3];
  const float* br1 = (const float*)d_in[4];
  const float* Wr2 = (const float*)d_in[5];
  const float* br2 = (const float*)d_in[6];
  const float* W1  = (const float*)d_in[7];
  const float* b1  = (const float*)d_in[8];
  const float* W2  = (const float*)d_in[9];
  const float* b2  = (const float*)d_in[10];
  float* out = (float*)d_out;

  // ws layout (BYTES):
  // r1 [0,131072) r2 [131072,262144) RW [262144,298496)
  // W1s [298496,429568) W2s [429568,495104)
  // counts [495104,495120) cursors [495120,495136) table [495136,495156)
  // list [495168, 495168+1050608)
  // pairs16 [2097152, 2097152+33554432)  (bf16 pair rows, new-path only)
  unsigned char* r1 = (unsigned char*)d_ws;
  unsigned char* r2 = r1 + B_N;
  float* RW  = (float*)((char*)d_ws + 262144);
  short* W1s = (short*)((char*)d_ws + 298496);
  short* W2s = (short*)((char*)d_ws + 429568);
  unsigned int* counts  = (unsigned int*)((char*)d_ws + 495104);
  unsigned int* cursors = (unsigned int*)((char*)d_ws + 495120);
  unsigned int* table   = (unsigned int*)((char*)d_ws + 495136);
  unsigned int* list    = (unsigned int*)((char*)d_ws + 495168);
  unsigned short* pairs16 = (unsigned short*)((char*)d_ws + 2097152);

  bool fast = (ws_size >= (size_t)2097152 + (size_t)B_N * 256);

  prepack2_k<<<64, 256, 0, stream>>>(Wr1, br1, Wr2, br2, W1, W2, RW, W1s, W2s,
                                     counts, cursors);
  router11b_k<<<B_N / 64, 256, 0, stream>>>(a, bv, pos, RW, r1, r2, counts,
                                            pairs16, fast ? 1 : 0);
  if (fast) {
    place2_k<<<B_N / 256, 256, 0, stream>>>(r1, r2, counts, cursors, list);
    expert4_k<<<2052, 256, 0, stream>>>(pairs16, W1s, W2s, b1, b2, counts, list, out);
  } else {
    offsets_k<<<1, 256, 0, stream>>>(counts, table, cursors, list);
    place_k<<<B_N / 256, 256, 0, stream>>>(r1, r2, cursors, list);
    expert3_k<<<2052, 256, 0, stream>>>(a, bv, W1s, W2s, b1, b2, table, list, out);
  }
}